// Round 4
// baseline (42452.850 us; speedup 1.0000x reference)
//
#include <hip/hip_runtime.h>
#include <hip/hip_cooperative_groups.h>
#include <cstdint>
#include <math.h>

namespace cg = cooperative_groups;

#define B_ 512
#define S_ 100
#define E_ 256
#define H_ 256

__device__ __forceinline__ float sigmoidf_(float x){ return 1.0f/(1.0f+expf(-x)); }

// Threefry-2x32, 20 rounds — matches jax/_src/prng.py lowering exactly.
__device__ __forceinline__ void threefry2x32_(uint32_t k0, uint32_t k1,
                                              uint32_t c0, uint32_t c1,
                                              uint32_t& o0, uint32_t& o1){
  uint32_t ks2 = k0 ^ k1 ^ 0x1BD11BDAu;
  uint32_t x0 = c0 + k0, x1 = c1 + k1;
#define ROT_(x,d) (((x)<<(d))|((x)>>(32-(d))))
#define RND_(r) { x0 += x1; x1 = ROT_(x1,(r)); x1 ^= x0; }
  RND_(13) RND_(15) RND_(26) RND_(6)  x0 += k1;  x1 += ks2 + 1u;
  RND_(17) RND_(29) RND_(16) RND_(24) x0 += ks2; x1 += k0  + 2u;
  RND_(13) RND_(15) RND_(26) RND_(6)  x0 += k0;  x1 += k1  + 3u;
  RND_(17) RND_(29) RND_(16) RND_(24) x0 += k1;  x1 += ks2 + 4u;
  RND_(13) RND_(15) RND_(26) RND_(6)  x0 += ks2; x1 += k0  + 5u;
#undef RND_
#undef ROT_
  o0 = x0; o1 = x1;
}

__device__ __forceinline__ float gumbel_bits_(uint32_t bits){
  const float tiny = 1.175494350822287508e-38f;
  float u = __uint_as_float((bits >> 9) | 0x3f800000u) - 1.0f; // [0,1)
  u = fmaxf(tiny, u + tiny);
  return -logf(-logf(u));
}

__device__ __forceinline__ float wsum_(float v){
  #pragma unroll
  for (int d = 32; d > 0; d >>= 1) v += __shfl_xor(v, d, 64);
  return v;
}
__device__ __forceinline__ float wmax_(float v){
  #pragma unroll
  for (int d = 32; d > 0; d >>= 1) v = fmaxf(v, __shfl_xor(v, d, 64));
  return v;
}

struct KParams {
  const float *inputs, *emb;
  const float *eWih, *eWhh, *ebih, *ebhh;
  const float *dWih, *dWhh, *dbih, *dbhh;
  const float *gWq, *gbq, *gWr, *gbr, *gV;
  const float *pWq, *pbq, *pWr, *pbr, *pV;
  const float *start;
  float *W4E, *W4D, *b4E, *b4D, *gWqT, *pWqT, *gWrT, *pWrT;
  float *enc, *refg, *refp, *h0, *h1, *c;
  float *probs, *idxo;
  int *mask, *sel;
};

union SMem {
  float xs[4096];                                   // lstm staging [k(512)][row(8)]
  struct { float As[8][128]; float Bs[8][128]; } g; // gemm tiles
  struct {
    float qq[2][256]; float q[2][256]; float pq[2][256];
    float lg[128]; float alpha[2][128]; float lp[128];
  } a;
};

// ---------- LSTM phase: 256 blocks = 64 row-groups(8 rows) x 4 unit-groups(64 u) ----------
__device__ void lstm_phase(const KParams& P, SMem& sm,
                           const float* __restrict__ W4, const float* __restrict__ b4,
                           const float* __restrict__ hr, float* __restrict__ hw,
                           float* __restrict__ cst, float* enc_out, int t, int mode)
{
  const int tid = threadIdx.x;
  const int uu  = tid & 63;
  const int rg  = tid >> 6;
  const int b0  = (blockIdx.x >> 2) * 8;
  const int u0  = (blockIdx.x & 3) * 64;

  for (int i = tid; i < 4096; i += 256) {
    const int k = i >> 3, r = i & 7, b = b0 + r;
    float v;
    if (k < 256) {
      if (mode == 0) {
        v = P.inputs[b*200 + t]*P.emb[k] + P.inputs[b*200 + 100 + t]*P.emb[256 + k];
      } else {
        const int s = P.sel[b];
        if (s < 0) v = P.start[k];
        else       v = P.inputs[b*200 + s]*P.emb[k] + P.inputs[b*200 + 100 + s]*P.emb[256 + k];
      }
    } else {
      v = hr[b*256 + (k - 256)];
    }
    sm.xs[i] = v;
  }
  __syncthreads();

  float a0x=0.f,a0y=0.f,a0z=0.f,a0w=0.f, a1x=0.f,a1y=0.f,a1z=0.f,a1w=0.f;
  const float* wp = W4 + (size_t)(u0 + uu)*4;
  #pragma unroll 4
  for (int k = 0; k < 512; ++k) {
    const float4 w = *(const float4*)(wp + (size_t)k*1024);
    const float2 x = *(const float2*)(sm.xs + k*8 + rg*2);
    a0x += x.x*w.x; a0y += x.x*w.y; a0z += x.x*w.z; a0w += x.x*w.w;
    a1x += x.y*w.x; a1y += x.y*w.y; a1z += x.y*w.z; a1w += x.y*w.w;
  }

  const float4 bb = *(const float4*)(b4 + (u0 + uu)*4);
  const int u = u0 + uu;
  {
    const int b = b0 + rg*2;
    const float gi = a0x + bb.x, gf = a0y + bb.y, gg = a0z + bb.z, go = a0w + bb.w;
    const float cN = sigmoidf_(gf)*cst[b*256+u] + sigmoidf_(gi)*tanhf(gg);
    const float hN = sigmoidf_(go)*tanhf(cN);
    cst[b*256+u] = cN; hw[b*256+u] = hN;
    if (mode == 0) enc_out[((size_t)b*S_ + t)*H_ + u] = hN;
  }
  {
    const int b = b0 + rg*2 + 1;
    const float gi = a1x + bb.x, gf = a1y + bb.y, gg = a1z + bb.z, go = a1w + bb.w;
    const float cN = sigmoidf_(gf)*cst[b*256+u] + sigmoidf_(gi)*tanhf(gg);
    const float hN = sigmoidf_(go)*tanhf(cN);
    cst[b*256+u] = cN; hw[b*256+u] = hN;
    if (mode == 0) enc_out[((size_t)b*S_ + t)*H_ + u] = hN;
  }
  __syncthreads();
}

// ---------- fused per-b attention mega-phase: block owns b0=2*bid, b0+1 ----------
__device__ void attn_phase(const KParams& P, SMem& sm, const float* __restrict__ h, int t)
{
  const int tid = threadIdx.x, lane = tid & 63, wv = tid >> 6;
  const int b0 = blockIdx.x * 2;

  { // qq = g_bq + h @ g_Wq^T  (both b share the weight stream)
    float a0 = P.gbq[tid], a1 = a0;
    const float* h0r = h + (size_t)b0*256;
    const float* h1r = h + (size_t)(b0+1)*256;
    #pragma unroll 4
    for (int k = 0; k < 256; ++k) {
      const float w = P.gWqT[k*256 + tid];
      a0 += h0r[k]*w; a1 += h1r[k]*w;
    }
    sm.a.qq[0][tid] = a0; sm.a.qq[1][tid] = a1;
  }
  __syncthreads();

  // glimpse logits + softmax per b
  for (int bb = 0; bb < 2; ++bb) {
    const float* rg = P.refg + (size_t)(b0+bb)*S_*H_;
    const int* mk = P.mask + (b0+bb)*S_;
    for (int is = 0; is < 25; ++is) {
      const int s = is*4 + wv;
      float pp = 0.f;
      #pragma unroll
      for (int j = 0; j < 4; ++j) {
        const int hh = lane + 64*j;
        pp += P.gV[hh] * tanhf(sm.a.qq[bb][hh] + rg[s*256 + hh]);
      }
      pp = wsum_(pp);
      if (lane == 0) sm.a.lg[s] = mk[s] ? -INFINITY : pp;
    }
    __syncthreads();
    if (wv == 0) {
      const float v0 = sm.a.lg[lane];
      const float v1 = (lane + 64 < S_) ? sm.a.lg[lane + 64] : -INFINITY;
      const float m  = wmax_(fmaxf(v0, v1));
      const float e0 = expf(v0 - m);
      const float e1 = (lane + 64 < S_) ? expf(v1 - m) : 0.f;
      const float smm = wsum_(e0 + e1);
      sm.a.alpha[bb][lane] = e0 / smm;
      if (lane + 64 < S_) sm.a.alpha[bb][lane + 64] = e1 / smm;
    }
    __syncthreads();
  }

  { // q = alpha @ enc
    const float* e0p = P.enc + (size_t)b0*S_*H_;
    const float* e1p = P.enc + (size_t)(b0+1)*S_*H_;
    float a0 = 0.f, a1 = 0.f;
    for (int s = 0; s < S_; ++s) {
      a0 += sm.a.alpha[0][s] * e0p[s*256 + tid];
      a1 += sm.a.alpha[1][s] * e1p[s*256 + tid];
    }
    sm.a.q[0][tid] = a0; sm.a.q[1][tid] = a1;
  }
  __syncthreads();

  { // pq = p_bq + q @ p_Wq^T
    float a0 = P.pbq[tid], a1 = a0;
    #pragma unroll 4
    for (int k = 0; k < 256; ++k) {
      const float w = P.pWqT[k*256 + tid];
      a0 += sm.a.q[0][k]*w; a1 += sm.a.q[1][k]*w;
    }
    sm.a.pq[0][tid] = a0; sm.a.pq[1][tid] = a1;
  }
  __syncthreads();

  // pointer logits + probs + sample per b
  for (int bb = 0; bb < 2; ++bb) {
    const int b = b0 + bb;
    const float* rp = P.refp + (size_t)b*S_*H_;
    const int* mk = P.mask + b*S_;
    for (int is = 0; is < 25; ++is) {
      const int s = is*4 + wv;
      float pp = 0.f;
      #pragma unroll
      for (int j = 0; j < 4; ++j) {
        const int hh = lane + 64*j;
        pp += P.pV[hh] * tanhf(sm.a.pq[bb][hh] + rp[s*256 + hh]);
      }
      pp = wsum_(pp);
      if (lane == 0) {
        const float v = 10.0f * tanhf(pp);
        sm.a.lp[s] = mk[s] ? -INFINITY : v;
      }
    }
    __syncthreads();
    if (wv == 0) {
      const float v0 = sm.a.lp[lane];
      const float v1 = (lane + 64 < S_) ? sm.a.lp[lane + 64] : -INFINITY;
      const float m  = wmax_(fmaxf(v0, v1));
      const float e0 = expf(v0 - m);
      const float e1 = (lane + 64 < S_) ? expf(v1 - m) : 0.f;
      const float smm = wsum_(e0 + e1);
      float* po = P.probs + ((size_t)t*B_ + b)*S_;
      po[lane] = e0 / smm;
      if (lane + 64 < S_) po[lane + 64] = e1 / smm;

      uint32_t k0, k1; threefry2x32_(0u, 1u, 0u, (uint32_t)t, k0, k1);
      uint32_t r0, r1;
      threefry2x32_(k0, k1, 0u, (uint32_t)(b*S_ + lane), r0, r1);
      float z0 = v0 + gumbel_bits_(r0 ^ r1);
      float z1 = -INFINITY;
      if (lane + 64 < S_) {
        uint32_t q0, q1;
        threefry2x32_(k0, k1, 0u, (uint32_t)(b*S_ + lane + 64), q0, q1);
        z1 = v1 + gumbel_bits_(q0 ^ q1);
      }
      float bv; int bi;
      if (z1 > z0) { bv = z1; bi = lane + 64; } else { bv = z0; bi = lane; }
      #pragma unroll
      for (int d = 32; d > 0; d >>= 1) {
        const float ov = __shfl_xor(bv, d, 64);
        const int   oi = __shfl_xor(bi, d, 64);
        if (ov > bv || (ov == bv && oi < bi)) { bv = ov; bi = oi; }
      }
      if (lane == 0) {
        P.idxo[t*B_ + b] = (float)bi;
        P.sel[b] = bi;
        P.mask[b*S_ + bi] = 1;
      }
    }
    __syncthreads();
  }
}

// ---------- one 128x128 GEMM tile: C = A@Bt + bias ----------
__device__ void gemm_tile(SMem& sm, const float* __restrict__ A, const float* __restrict__ Bt,
                          const float* __restrict__ bias, float* __restrict__ C,
                          int m0, int n0)
{
  const int tid = threadIdx.x;
  float acc[8][8] = {};
  const int tx = tid & 15, ty = tid >> 4;

  for (int k0 = 0; k0 < 256; k0 += 8) {
    {
      const int row = tid >> 1, q = tid & 1;
      const float4 av = *(const float4*)(A + (size_t)(m0+row)*256 + k0 + q*4);
      sm.g.As[q*4+0][row] = av.x; sm.g.As[q*4+1][row] = av.y;
      sm.g.As[q*4+2][row] = av.z; sm.g.As[q*4+3][row] = av.w;
    }
    {
      const int kk = tid >> 5, nq = tid & 31;
      *(float4*)(&sm.g.Bs[kk][nq*4]) = *(const float4*)(Bt + (size_t)(k0+kk)*256 + n0 + nq*4);
    }
    __syncthreads();
    #pragma unroll
    for (int k = 0; k < 8; ++k) {
      float a[8], bb[8];
      *(float4*)&a[0]  = *(const float4*)&sm.g.As[k][ty*8];
      *(float4*)&a[4]  = *(const float4*)&sm.g.As[k][ty*8+4];
      *(float4*)&bb[0] = *(const float4*)&sm.g.Bs[k][tx*8];
      *(float4*)&bb[4] = *(const float4*)&sm.g.Bs[k][tx*8+4];
      #pragma unroll
      for (int i = 0; i < 8; ++i)
        #pragma unroll
        for (int j = 0; j < 8; ++j)
          acc[i][j] += a[i]*bb[j];
    }
    __syncthreads();
  }
  #pragma unroll
  for (int i = 0; i < 8; ++i) {
    const int m = m0 + ty*8 + i;
    #pragma unroll
    for (int j = 0; j < 8; j += 4) {
      const int n = n0 + tx*8 + j;
      float4 o;
      o.x = acc[i][j  ] + bias[n  ];
      o.y = acc[i][j+1] + bias[n+1];
      o.z = acc[i][j+2] + bias[n+2];
      o.w = acc[i][j+3] + bias[n+3];
      *(float4*)(C + (size_t)m*256 + n) = o;
    }
  }
  __syncthreads();
}

// ---------- the single persistent cooperative kernel ----------
__global__ __launch_bounds__(256) void pointer_net_mono(KParams P)
{
  cg::grid_group gg = cg::this_grid();
  __shared__ SMem sm;
  const int tid = threadIdx.x;
  const int gtid = blockIdx.x*256 + tid;     // 0..65535

  // ---- Phase 0: prep ----
  for (int i = gtid; i < 512*1024; i += 65536) {
    const int g = i & 3, u = (i >> 2) & 255, k = i >> 10;
    const int row = g*256 + u;
    P.W4E[i] = (k < 256) ? P.eWih[row*256 + k] : P.eWhh[row*256 + (k-256)];
    P.W4D[i] = (k < 256) ? P.dWih[row*256 + k] : P.dWhh[row*256 + (k-256)];
  }
  if (gtid < 1024) {
    const int g = gtid & 3, u = gtid >> 2;
    P.b4E[gtid] = P.ebih[g*256 + u] + P.ebhh[g*256 + u];
    P.b4D[gtid] = P.dbih[g*256 + u] + P.dbhh[g*256 + u];
  }
  {
    const int r = gtid >> 8, cc = gtid & 255;
    P.gWqT[gtid] = P.gWq[cc*256 + r];
    P.pWqT[gtid] = P.pWq[cc*256 + r];
    P.gWrT[gtid] = P.gWr[cc*256 + r];
    P.pWrT[gtid] = P.pWr[cc*256 + r];
  }
  for (int i = gtid; i < B_*H_; i += 65536) { P.h0[i] = 0.f; P.c[i] = 0.f; }
  if (gtid < B_*S_) P.mask[gtid] = 0;
  if (gtid < B_)    P.sel[gtid]  = -1;
  __threadfence(); gg.sync();

  float* hp[2] = { P.h0, P.h1 };
  int p = 0;

  // ---- Phase 1: encoder, 100 steps ----
  for (int t = 0; t < S_; ++t) {
    lstm_phase(P, sm, P.W4E, P.b4E, hp[p], hp[p^1], P.c, P.enc, t, 0);
    p ^= 1;
    __threadfence(); gg.sync();
  }

  // ---- Phase 2: ref_g / ref_p projections (1600 tiles over 256 blocks) ----
  for (int job = blockIdx.x; job < 1600; job += 256) {
    const float* Bt   = (job < 800) ? P.gWrT : P.pWrT;
    const float* bias = (job < 800) ? P.gbr  : P.pbr;
    float* C          = (job < 800) ? P.refg : P.refp;
    const int jj = job % 800;
    gemm_tile(sm, P.enc, Bt, bias, C, (jj % 400)*128, (jj / 400)*128);
  }
  __threadfence(); gg.sync();

  // ---- Phase 3: decoder, 100 steps ----
  for (int t = 0; t < S_; ++t) {
    lstm_phase(P, sm, P.W4D, P.b4D, hp[p], hp[p^1], P.c, nullptr, t, 1);
    p ^= 1;
    __threadfence(); gg.sync();
    attn_phase(P, sm, hp[p], t);
    __threadfence(); gg.sync();
  }
}

extern "C" void kernel_launch(void* const* d_in, const int* in_sizes, int n_in,
                              void* d_out, int out_size, void* d_ws, size_t ws_size,
                              hipStream_t stream) {
  (void)in_sizes; (void)n_in; (void)out_size; (void)ws_size;

  float* ws = (float*)d_ws;
  size_t o = 0;
  float* W4E  = ws + o; o += (size_t)512*1024;
  float* W4D  = ws + o; o += (size_t)512*1024;
  float* b4E  = ws + o; o += 1024;
  float* b4D  = ws + o; o += 1024;
  float* gWqT = ws + o; o += 65536;
  float* pWqT = ws + o; o += 65536;
  float* gWrT = ws + o; o += 65536;
  float* pWrT = ws + o; o += 65536;
  float* enc  = ws + o; o += (size_t)B_*S_*H_;
  float* refg = ws + o; o += (size_t)B_*S_*H_;
  float* refp = ws + o; o += (size_t)B_*S_*H_;
  float* h0   = ws + o; o += (size_t)B_*H_;
  float* h1   = ws + o; o += (size_t)B_*H_;
  float* c    = ws + o; o += (size_t)B_*H_;
  int* mask   = (int*)(ws + o); o += (size_t)B_*S_;
  int* sel    = (int*)(ws + o); o += B_;

  KParams P;
  P.inputs = (const float*)d_in[0];
  P.emb    = (const float*)d_in[1];
  P.eWih   = (const float*)d_in[2];
  P.eWhh   = (const float*)d_in[3];
  P.ebih   = (const float*)d_in[4];
  P.ebhh   = (const float*)d_in[5];
  P.dWih   = (const float*)d_in[6];
  P.dWhh   = (const float*)d_in[7];
  P.dbih   = (const float*)d_in[8];
  P.dbhh   = (const float*)d_in[9];
  P.gWq    = (const float*)d_in[10];
  P.gbq    = (const float*)d_in[11];
  P.gWr    = (const float*)d_in[12];
  P.gbr    = (const float*)d_in[13];
  P.gV     = (const float*)d_in[14];
  P.pWq    = (const float*)d_in[15];
  P.pbq    = (const float*)d_in[16];
  P.pWr    = (const float*)d_in[17];
  P.pbr    = (const float*)d_in[18];
  P.pV     = (const float*)d_in[19];
  P.start  = (const float*)d_in[20];
  P.W4E = W4E; P.W4D = W4D; P.b4E = b4E; P.b4D = b4D;
  P.gWqT = gWqT; P.pWqT = pWqT; P.gWrT = gWrT; P.pWrT = pWrT;
  P.enc = enc; P.refg = refg; P.refp = refp;
  P.h0 = h0; P.h1 = h1; P.c = c;
  P.probs = (float*)d_out;
  P.idxo  = P.probs + (size_t)S_*B_*S_;
  P.mask = mask; P.sel = sel;

  void* kargs[] = { (void*)&P };
  hipLaunchCooperativeKernel((const void*)pointer_net_mono, dim3(256), dim3(256),
                             kargs, 0, stream);
}

// Round 5
// 23280.807 us; speedup vs baseline: 1.8235x; 1.8235x over previous
//
#include <hip/hip_runtime.h>
#include <cstdint>
#include <math.h>

#define B_ 512
#define S_ 100
#define E_ 256
#define H_ 256

__device__ __forceinline__ float sigmoidf_(float x){ return 1.0f/(1.0f+expf(-x)); }

// Threefry-2x32, 20 rounds — matches jax/_src/prng.py lowering exactly.
__device__ __forceinline__ void threefry2x32_(uint32_t k0, uint32_t k1,
                                              uint32_t c0, uint32_t c1,
                                              uint32_t& o0, uint32_t& o1){
  uint32_t ks2 = k0 ^ k1 ^ 0x1BD11BDAu;
  uint32_t x0 = c0 + k0, x1 = c1 + k1;
#define ROT_(x,d) (((x)<<(d))|((x)>>(32-(d))))
#define RND_(r) { x0 += x1; x1 = ROT_(x1,(r)); x1 ^= x0; }
  RND_(13) RND_(15) RND_(26) RND_(6)  x0 += k1;  x1 += ks2 + 1u;
  RND_(17) RND_(29) RND_(16) RND_(24) x0 += ks2; x1 += k0  + 2u;
  RND_(13) RND_(15) RND_(26) RND_(6)  x0 += k0;  x1 += k1  + 3u;
  RND_(17) RND_(29) RND_(16) RND_(24) x0 += k1;  x1 += ks2 + 4u;
  RND_(13) RND_(15) RND_(26) RND_(6)  x0 += ks2; x1 += k0  + 5u;
#undef RND_
#undef ROT_
  o0 = x0; o1 = x1;
}

__device__ __forceinline__ float gumbel_bits_(uint32_t bits){
  const float tiny = 1.175494350822287508e-38f;
  float u = __uint_as_float((bits >> 9) | 0x3f800000u) - 1.0f; // [0,1)
  u = fmaxf(tiny, u + tiny);
  return -logf(-logf(u));
}

__device__ __forceinline__ float wsum_(float v){
  #pragma unroll
  for (int d = 32; d > 0; d >>= 1) v += __shfl_xor(v, d, 64);
  return v;
}
__device__ __forceinline__ float wmax_(float v){
  #pragma unroll
  for (int d = 32; d > 0; d >>= 1) v = fmaxf(v, __shfl_xor(v, d, 64));
  return v;
}

struct KParams {
  const float *inputs, *emb;
  const float *gbq, *gV, *pbq, *pV;
  const float *gbr, *pbr;
  const float *start;
  const float *W4E, *W4D, *b4E, *b4D, *gWqT, *pWqT, *gWrT, *pWrT;
  float *enc, *refg, *refp;
  float *probs, *idxo;
};

struct PrepParams {
  const float *eWih, *eWhh, *ebih, *ebhh;
  const float *dWih, *dWhh, *dbih, *dbhh;
  const float *gWq, *pWq, *gWr, *pWr;
  float *W4E, *W4D, *b4E, *b4D, *gWqT, *pWqT, *gWrT, *pWrT;
};

// ---------- single fused prep kernel ----------
__global__ __launch_bounds__(256) void prep_all(PrepParams P){
  const int i = blockIdx.x*256 + threadIdx.x;        // 0 .. 524287
  {
    const int g = i & 3, u = (i >> 2) & 255, k = i >> 10;
    const int row = g*256 + u;
    P.W4E[i] = (k < 256) ? P.eWih[row*256 + k] : P.eWhh[row*256 + (k-256)];
    P.W4D[i] = (k < 256) ? P.dWih[row*256 + k] : P.dWhh[row*256 + (k-256)];
  }
  if (i < 65536) {
    const int r = i >> 8, cc = i & 255;
    P.gWqT[i] = P.gWq[cc*256 + r];
    P.pWqT[i] = P.pWq[cc*256 + r];
    P.gWrT[i] = P.gWr[cc*256 + r];
    P.pWrT[i] = P.pWr[cc*256 + r];
  }
  if (i < 1024) {
    const int g = i & 3, u = i >> 2;
    P.b4E[i] = P.ebih[g*256 + u] + P.ebhh[g*256 + u];
    P.b4D[i] = P.dbih[g*256 + u] + P.dbhh[g*256 + u];
  }
}

// ---------- THE kernel: block owns batch rows 2*bid, 2*bid+1 end-to-end ----------
__global__ __launch_bounds__(256, 1) void pointer_net_perb(KParams P)
{
  const int tid  = threadIdx.x;
  const int u    = tid;
  const int lane = tid & 63;
  const int wv   = tid >> 6;
  const int b0   = blockIdx.x * 2;

  __shared__ float embL[512];
  __shared__ float xs[512];        // [k][r]   r=0,1
  __shared__ float hs[512];        // [u][r]
  __shared__ float es[20*256];     // refproj staging [s][k]
  __shared__ float qqL[512];       // [bb][u]
  __shared__ float qL[512];
  __shared__ float pqL[512];
  __shared__ float lgL[128];
  __shared__ float alphaL[256];    // [bb][s(128)]
  __shared__ float lpL[128];
  __shared__ int   maskL[256];     // [bb][s(128)]
  __shared__ int   selL[2];

  // ---- init block-local state ----
  embL[tid]       = P.emb[tid];
  embL[256 + tid] = P.emb[256 + tid];
  maskL[tid] = 0;
  if (tid < 2) selL[tid] = -1;
  hs[tid*2] = 0.f; hs[tid*2 + 1] = 0.f;
  float c0 = 0.f, c1 = 0.f;
  __syncthreads();

  // =============== Phase 1: encoder, 100 steps ===============
  for (int t = 0; t < S_; ++t) {
    // stage x for both rows: xs[k*2+r]
    for (int i = tid; i < 512; i += 256) {
      const int k = i >> 1, r = i & 1, b = b0 + r;
      xs[i] = P.inputs[b*200 + t]*embL[k] + P.inputs[b*200 + 100 + t]*embL[256 + k];
    }
    __syncthreads();

    float a0x=0.f,a0y=0.f,a0z=0.f,a0w=0.f, a1x=0.f,a1y=0.f,a1z=0.f,a1w=0.f;
    const float* wp = P.W4E + (size_t)u*4;
    #pragma unroll 8
    for (int k = 0; k < 256; ++k) {
      const float4 w = *(const float4*)(wp + (size_t)k*1024);
      const float2 x = *(const float2*)(xs + k*2);
      a0x += x.x*w.x; a0y += x.x*w.y; a0z += x.x*w.z; a0w += x.x*w.w;
      a1x += x.y*w.x; a1y += x.y*w.y; a1z += x.y*w.z; a1w += x.y*w.w;
    }
    #pragma unroll 8
    for (int k = 256; k < 512; ++k) {
      const float4 w = *(const float4*)(wp + (size_t)k*1024);
      const float2 x = *(const float2*)(hs + (k - 256)*2);
      a0x += x.x*w.x; a0y += x.x*w.y; a0z += x.x*w.z; a0w += x.x*w.w;
      a1x += x.y*w.x; a1y += x.y*w.y; a1z += x.y*w.z; a1w += x.y*w.w;
    }
    __syncthreads();   // all reads of hs/xs done before overwrite

    const float4 bb4 = *(const float4*)(P.b4E + u*4);
    {
      const float gi = a0x + bb4.x, gf = a0y + bb4.y, gg = a0z + bb4.z, go = a0w + bb4.w;
      const float cN = sigmoidf_(gf)*c0 + sigmoidf_(gi)*tanhf(gg);
      const float hN = sigmoidf_(go)*tanhf(cN);
      c0 = cN; hs[u*2] = hN;
      P.enc[((size_t)b0*S_ + t)*H_ + u] = hN;
    }
    {
      const float gi = a1x + bb4.x, gf = a1y + bb4.y, gg = a1z + bb4.z, go = a1w + bb4.w;
      const float cN = sigmoidf_(gf)*c1 + sigmoidf_(gi)*tanhf(gg);
      const float hN = sigmoidf_(go)*tanhf(cN);
      c1 = cN; hs[u*2 + 1] = hN;
      P.enc[((size_t)(b0+1)*S_ + t)*H_ + u] = hN;
    }
    __syncthreads();   // hs visible for next step's k-loop
  }

  // =============== Phase 2: ref_g / ref_p projections (own rows) ===============
  for (int bb = 0; bb < 2; ++bb) {
    const int b = b0 + bb;
    for (int s0 = 0; s0 < S_; s0 += 20) {
      for (int i = tid; i < 20*256; i += 256)
        es[i] = P.enc[((size_t)b*S_ + s0 + (i >> 8))*H_ + (i & 255)];
      __syncthreads();
      float accg[20], accp[20];
      #pragma unroll
      for (int s = 0; s < 20; ++s) { accg[s] = 0.f; accp[s] = 0.f; }
      #pragma unroll 4
      for (int k = 0; k < 256; ++k) {
        const float wg = P.gWrT[k*256 + u];
        const float wpv = P.pWrT[k*256 + u];
        #pragma unroll
        for (int s = 0; s < 20; ++s) {
          const float xk = es[s*256 + k];
          accg[s] += xk*wg; accp[s] += xk*wpv;
        }
      }
      const float bg = P.gbr[u], bp = P.pbr[u];
      #pragma unroll
      for (int s = 0; s < 20; ++s) {
        P.refg[((size_t)b*S_ + s0 + s)*H_ + u] = accg[s] + bg;
        P.refp[((size_t)b*S_ + s0 + s)*H_ + u] = accp[s] + bp;
      }
      __syncthreads();
    }
  }

  // =============== Phase 3: decoder, 100 steps ===============
  for (int t = 0; t < S_; ++t) {
    // ---- LSTM ----
    for (int i = tid; i < 512; i += 256) {
      const int k = i >> 1, r = i & 1, b = b0 + r;
      const int s = selL[r];
      float v;
      if (s < 0) v = P.start[k];
      else       v = P.inputs[b*200 + s]*embL[k] + P.inputs[b*200 + 100 + s]*embL[256 + k];
      xs[i] = v;
    }
    __syncthreads();

    float a0x=0.f,a0y=0.f,a0z=0.f,a0w=0.f, a1x=0.f,a1y=0.f,a1z=0.f,a1w=0.f;
    const float* wp = P.W4D + (size_t)u*4;
    #pragma unroll 8
    for (int k = 0; k < 256; ++k) {
      const float4 w = *(const float4*)(wp + (size_t)k*1024);
      const float2 x = *(const float2*)(xs + k*2);
      a0x += x.x*w.x; a0y += x.x*w.y; a0z += x.x*w.z; a0w += x.x*w.w;
      a1x += x.y*w.x; a1y += x.y*w.y; a1z += x.y*w.z; a1w += x.y*w.w;
    }
    #pragma unroll 8
    for (int k = 256; k < 512; ++k) {
      const float4 w = *(const float4*)(wp + (size_t)k*1024);
      const float2 x = *(const float2*)(hs + (k - 256)*2);
      a0x += x.x*w.x; a0y += x.x*w.y; a0z += x.x*w.z; a0w += x.x*w.w;
      a1x += x.y*w.x; a1y += x.y*w.y; a1z += x.y*w.z; a1w += x.y*w.w;
    }
    __syncthreads();

    const float4 bb4 = *(const float4*)(P.b4D + u*4);
    {
      const float gi = a0x + bb4.x, gf = a0y + bb4.y, gg = a0z + bb4.z, go = a0w + bb4.w;
      const float cN = sigmoidf_(gf)*c0 + sigmoidf_(gi)*tanhf(gg);
      const float hN = sigmoidf_(go)*tanhf(cN);
      c0 = cN; hs[u*2] = hN;
    }
    {
      const float gi = a1x + bb4.x, gf = a1y + bb4.y, gg = a1z + bb4.z, go = a1w + bb4.w;
      const float cN = sigmoidf_(gf)*c1 + sigmoidf_(gi)*tanhf(gg);
      const float hN = sigmoidf_(go)*tanhf(cN);
      c1 = cN; hs[u*2 + 1] = hN;
    }
    __syncthreads();   // hs visible for attention

    // ---- attention: qq = g_bq + h @ g_Wq^T ----
    {
      float a0 = P.gbq[tid], a1 = a0;
      #pragma unroll 4
      for (int k = 0; k < 256; ++k) {
        const float w = P.gWqT[k*256 + tid];
        a0 += hs[k*2]*w; a1 += hs[k*2 + 1]*w;
      }
      qqL[tid] = a0; qqL[256 + tid] = a1;
    }
    __syncthreads();

    // glimpse logits + softmax per b
    for (int bb = 0; bb < 2; ++bb) {
      const float* rg = P.refg + (size_t)(b0+bb)*S_*H_;
      const int* mk = maskL + bb*128;
      for (int is = 0; is < 25; ++is) {
        const int s = is*4 + wv;
        float pp = 0.f;
        #pragma unroll
        for (int j = 0; j < 4; ++j) {
          const int hh = lane + 64*j;
          pp += P.gV[hh] * tanhf(qqL[bb*256 + hh] + rg[s*256 + hh]);
        }
        pp = wsum_(pp);
        if (lane == 0) lgL[s] = mk[s] ? -INFINITY : pp;
      }
      __syncthreads();
      if (wv == 0) {
        const float v0 = lgL[lane];
        const float v1 = (lane + 64 < S_) ? lgL[lane + 64] : -INFINITY;
        const float m  = wmax_(fmaxf(v0, v1));
        const float e0 = expf(v0 - m);
        const float e1 = (lane + 64 < S_) ? expf(v1 - m) : 0.f;
        const float smm = wsum_(e0 + e1);
        alphaL[bb*128 + lane] = e0 / smm;
        if (lane + 64 < S_) alphaL[bb*128 + lane + 64] = e1 / smm;
      }
      __syncthreads();
    }

    // q = alpha @ enc
    {
      const float* e0p = P.enc + (size_t)b0*S_*H_;
      const float* e1p = P.enc + (size_t)(b0+1)*S_*H_;
      float a0 = 0.f, a1 = 0.f;
      for (int s = 0; s < S_; ++s) {
        a0 += alphaL[s]       * e0p[s*256 + tid];
        a1 += alphaL[128 + s] * e1p[s*256 + tid];
      }
      qL[tid] = a0; qL[256 + tid] = a1;
    }
    __syncthreads();

    // pq = p_bq + q @ p_Wq^T
    {
      float a0 = P.pbq[tid], a1 = a0;
      #pragma unroll 4
      for (int k = 0; k < 256; ++k) {
        const float w = P.pWqT[k*256 + tid];
        a0 += qL[k]*w; a1 += qL[256 + k]*w;
      }
      pqL[tid] = a0; pqL[256 + tid] = a1;
    }
    __syncthreads();

    // pointer logits + probs + sample per b
    for (int bb = 0; bb < 2; ++bb) {
      const int b = b0 + bb;
      const float* rp = P.refp + (size_t)b*S_*H_;
      const int* mk = maskL + bb*128;
      for (int is = 0; is < 25; ++is) {
        const int s = is*4 + wv;
        float pp = 0.f;
        #pragma unroll
        for (int j = 0; j < 4; ++j) {
          const int hh = lane + 64*j;
          pp += P.pV[hh] * tanhf(pqL[bb*256 + hh] + rp[s*256 + hh]);
        }
        pp = wsum_(pp);
        if (lane == 0) {
          const float v = 10.0f * tanhf(pp);
          lpL[s] = mk[s] ? -INFINITY : v;
        }
      }
      __syncthreads();
      if (wv == 0) {
        const float v0 = lpL[lane];
        const float v1 = (lane + 64 < S_) ? lpL[lane + 64] : -INFINITY;
        const float m  = wmax_(fmaxf(v0, v1));
        const float e0 = expf(v0 - m);
        const float e1 = (lane + 64 < S_) ? expf(v1 - m) : 0.f;
        const float smm = wsum_(e0 + e1);
        float* po = P.probs + ((size_t)t*B_ + b)*S_;
        po[lane] = e0 / smm;
        if (lane + 64 < S_) po[lane + 64] = e1 / smm;

        uint32_t k0, k1; threefry2x32_(0u, 1u, 0u, (uint32_t)t, k0, k1);
        uint32_t r0, r1;
        threefry2x32_(k0, k1, 0u, (uint32_t)(b*S_ + lane), r0, r1);
        float z0 = v0 + gumbel_bits_(r0 ^ r1);
        float z1 = -INFINITY;
        if (lane + 64 < S_) {
          uint32_t q0, q1;
          threefry2x32_(k0, k1, 0u, (uint32_t)(b*S_ + lane + 64), q0, q1);
          z1 = v1 + gumbel_bits_(q0 ^ q1);
        }
        float bv; int bi;
        if (z1 > z0) { bv = z1; bi = lane + 64; } else { bv = z0; bi = lane; }
        #pragma unroll
        for (int d = 32; d > 0; d >>= 1) {
          const float ov = __shfl_xor(bv, d, 64);
          const int   oi = __shfl_xor(bi, d, 64);
          if (ov > bv || (ov == bv && oi < bi)) { bv = ov; bi = oi; }
        }
        if (lane == 0) {
          P.idxo[t*B_ + b] = (float)bi;
          selL[bb] = bi;
          maskL[bb*128 + bi] = 1;
        }
      }
      __syncthreads();
    }
  }
}

extern "C" void kernel_launch(void* const* d_in, const int* in_sizes, int n_in,
                              void* d_out, int out_size, void* d_ws, size_t ws_size,
                              hipStream_t stream) {
  (void)in_sizes; (void)n_in; (void)out_size; (void)ws_size;

  float* ws = (float*)d_ws;
  size_t o = 0;
  float* W4E  = ws + o; o += (size_t)512*1024;
  float* W4D  = ws + o; o += (size_t)512*1024;
  float* b4E  = ws + o; o += 1024;
  float* b4D  = ws + o; o += 1024;
  float* gWqT = ws + o; o += 65536;
  float* pWqT = ws + o; o += 65536;
  float* gWrT = ws + o; o += 65536;
  float* pWrT = ws + o; o += 65536;
  float* enc  = ws + o; o += (size_t)B_*S_*H_;
  float* refg = ws + o; o += (size_t)B_*S_*H_;
  float* refp = ws + o; o += (size_t)B_*S_*H_;

  PrepParams PP;
  PP.eWih = (const float*)d_in[2];  PP.eWhh = (const float*)d_in[3];
  PP.ebih = (const float*)d_in[4];  PP.ebhh = (const float*)d_in[5];
  PP.dWih = (const float*)d_in[6];  PP.dWhh = (const float*)d_in[7];
  PP.dbih = (const float*)d_in[8];  PP.dbhh = (const float*)d_in[9];
  PP.gWq  = (const float*)d_in[10]; PP.pWq  = (const float*)d_in[15];
  PP.gWr  = (const float*)d_in[12]; PP.pWr  = (const float*)d_in[17];
  PP.W4E = W4E; PP.W4D = W4D; PP.b4E = b4E; PP.b4D = b4D;
  PP.gWqT = gWqT; PP.pWqT = pWqT; PP.gWrT = gWrT; PP.pWrT = pWrT;

  KParams P;
  P.inputs = (const float*)d_in[0];
  P.emb    = (const float*)d_in[1];
  P.gbq    = (const float*)d_in[11];
  P.gbr    = (const float*)d_in[13];
  P.gV     = (const float*)d_in[14];
  P.pbq    = (const float*)d_in[16];
  P.pbr    = (const float*)d_in[18];
  P.pV     = (const float*)d_in[19];
  P.start  = (const float*)d_in[20];
  P.W4E = W4E; P.W4D = W4D; P.b4E = b4E; P.b4D = b4D;
  P.gWqT = gWqT; P.pWqT = pWqT; P.gWrT = gWrT; P.pWrT = pWrT;
  P.enc = enc; P.refg = refg; P.refp = refp;
  P.probs = (float*)d_out;
  P.idxo  = P.probs + (size_t)S_*B_*S_;

  prep_all<<<2048, 256, 0, stream>>>(PP);
  pointer_net_perb<<<256, 256, 0, stream>>>(P);
}